// Round 2
// baseline (458.627 us; speedup 1.0000x reference)
//
#include <hip/hip_runtime.h>
#include <hip/hip_bf16.h>

// Problem constants (from reference)
#define M_TOTAL 65536   // N_IDS
#define ND      128     // N_DOCS
#define FDIM    220     // FEATURE_DIM
#define KPAD    224     // FDIM padded to multiple of 32 for MFMA
#define HID     768     // HIDDEN
#define G8      28      // groups of 8 cols per 224-col padded row

using bf16_t = __hip_bfloat16;
using bf16x8 = __attribute__((ext_vector_type(8))) short;  // 8 bf16 = 4 VGPRs
using f32x4  = __attribute__((ext_vector_type(4))) float;  // native vec4 (MFMA acc + IO)

struct __align__(16) bf16v8 { bf16_t v[8]; };

__device__ __forceinline__ float slog(float x) {
  return copysignf(log1pf(fabsf(x)), x);  // log(|x|+1) * sign(x)
}

__device__ __forceinline__ f32x4 slog4(f32x4 f) {
  f32x4 y;
  y[0] = slog(f[0]); y[1] = slog(f[1]); y[2] = slog(f[2]); y[3] = slog(f[3]);
  return y;
}

__device__ __forceinline__ bf16x8 pack8(f32x4 a, f32x4 b) {
  bf16v8 h;
  h.v[0] = __float2bfloat16(a[0]); h.v[1] = __float2bfloat16(a[1]);
  h.v[2] = __float2bfloat16(a[2]); h.v[3] = __float2bfloat16(a[3]);
  h.v[4] = __float2bfloat16(b[0]); h.v[5] = __float2bfloat16(b[1]);
  h.v[6] = __float2bfloat16(b[2]); h.v[7] = __float2bfloat16(b[3]);
  return __builtin_bit_cast(bf16x8, h);
}

// ---------------------------------------------------------------------------
// Kernel 1 (tiny): W [768x220] fp32 -> Wb [768x224] bf16 in d_ws. 84 blocks.
// ---------------------------------------------------------------------------
__global__ __launch_bounds__(256) void convert_w_kernel(
    const float* __restrict__ W, bf16_t* __restrict__ Wb)
{
  const int j   = blockIdx.x * 256 + threadIdx.x;  // exact: 768*28 = 84*256
  const int row = j / G8;
  const int g   = j % G8;

  const float* src = W + (size_t)row * FDIM + g * 8;
  const f32x4 f0 = *(const f32x4*)src;            // cols 216..219 ok for g=27
  f32x4 f1;
  if (g < 27) f1 = *(const f32x4*)(src + 4);
  else        { f1[0] = 0.f; f1[1] = 0.f; f1[2] = 0.f; f1[3] = 0.f; }  // pad 220..223
  *(bf16v8*)(Wb + (size_t)row * KPAD + g * 8) = __builtin_bit_cast(bf16v8, pack8(f0, f1));
}

// ---------------------------------------------------------------------------
// Kernel 2 (fused, barrier-free): each wave privately owns 32 rows.
//   Gather table rows DIRECTLY into MFMA A-fragments (registers): lane (q,l15)
//   holds A row l15, cols kb*32+q*8..+7 — exactly one f32x4-pair gather per
//   (mi,kb). slog in fp32, write fb (output 2) nontemporal, pack bf16 -> af.
//   No LDS, no __syncthreads, whole grid co-resident (2048 waves): gather
//   latency, MFMA, and the 259 MB store stream all overlap freely.
//   GEMM: 6 x 128-col N-tiles, acc[2][8], B from L2-resident Wb (344 KB).
// ---------------------------------------------------------------------------
__global__ __launch_bounds__(256, 2) void fused_gather_gemm_kernel(
    const int2* __restrict__ ids, const float* __restrict__ table,
    const bf16_t* __restrict__ Wb, const float* __restrict__ bias,
    float* __restrict__ out, float* __restrict__ fb)
{
  const int tid  = threadIdx.x;
  const int bm   = blockIdx.x;       // 0..511
  const int wave = tid >> 6;         // 0..3  -> owns rows wave*32..+31
  const int lane = tid & 63;
  const int l15  = lane & 15;
  const int q    = lane >> 4;

  const int rbase = bm * 128 + wave * 32;

  // ---- gather + slog + fb-write + pack, straight into A fragments ----
  bf16x8 af[7][2];
#pragma unroll
  for (int mi = 0; mi < 2; ++mi) {
    const int grow = rbase + mi * 16 + l15;
    const int2 p   = ids[grow];
    const float* srow = table + ((size_t)p.x * ND + p.y) * FDIM;
    float*       frow = fb + (size_t)grow * FDIM;
#pragma unroll
    for (int kb = 0; kb < 7; ++kb) {
      const int  c0   = kb * 32 + q * 8;
      const bool tail = (kb == 6) && (q == 3);   // cols 216..223: only 4 real
      f32x4 lo = *(const f32x4*)(srow + c0);
      f32x4 hi;
      if (!tail) hi = *(const f32x4*)(srow + c0 + 4);
      else       { hi[0] = 0.f; hi[1] = 0.f; hi[2] = 0.f; hi[3] = 0.f; }
      lo = slog4(lo);
      hi = slog4(hi);                             // slog(0)=0, pad stays 0
      __builtin_nontemporal_store(lo, (f32x4*)(frow + c0));
      if (!tail)
        __builtin_nontemporal_store(hi, (f32x4*)(frow + c0 + 4));
      af[kb][mi] = pack8(lo, hi);
    }
  }
  // no barrier: fragments are wave-private registers

  // ---- GEMM: 6 N-tiles of 128 cols; B rows bn*128 + ni*16 + l15 ----
  for (int bn = 0; bn < 6; ++bn) {
    f32x4 acc[2][8];
#pragma unroll
    for (int i = 0; i < 2; ++i)
#pragma unroll
      for (int j = 0; j < 8; ++j) acc[i][j] = (f32x4){0.f, 0.f, 0.f, 0.f};

    const bf16_t* Wbase = Wb + (size_t)(bn * 128 + l15) * KPAD + q * 8;

#pragma unroll
    for (int kb = 0; kb < 7; ++kb) {
      bf16x8 bg[8];
#pragma unroll
      for (int ni = 0; ni < 8; ++ni)
        bg[ni] = *(const bf16x8*)(Wbase + (size_t)ni * 16 * KPAD + kb * 32);
#pragma unroll
      for (int mi = 0; mi < 2; ++mi)
#pragma unroll
        for (int ni = 0; ni < 8; ++ni)
          acc[mi][ni] = __builtin_amdgcn_mfma_f32_16x16x32_bf16(
              af[kb][mi], bg[ni], acc[mi][ni], 0, 0, 0);
    }

    // epilogue: C/D layout col = lane&15, row = (lane>>4)*4 + reg [m89-verified]
    const int col0 = bn * 128 + l15;
    const int row0 = rbase + q * 4;

    float bv[8];
#pragma unroll
    for (int ni = 0; ni < 8; ++ni) bv[ni] = bias[col0 + ni * 16];

#pragma unroll
    for (int mi = 0; mi < 2; ++mi) {
#pragma unroll
      for (int r = 0; r < 4; ++r) {
        const size_t rowoff = (size_t)(row0 + mi * 16 + r) * HID;
#pragma unroll
        for (int ni = 0; ni < 8; ++ni) {   // ni innermost: adjacent 64B halves
          float v = acc[mi][ni][r] + bv[ni];
          v = v > 0.f ? v : 0.f;
          __builtin_nontemporal_store(v, out + rowoff + col0 + ni * 16);
        }
      }
    }
  }
}

extern "C" void kernel_launch(void* const* d_in, const int* in_sizes, int n_in,
                              void* d_out, int out_size, void* d_ws, size_t ws_size,
                              hipStream_t stream) {
  (void)in_sizes; (void)n_in; (void)out_size; (void)ws_size;

  const int2*  ids   = (const int2*)d_in[0];
  const float* table = (const float*)d_in[1];
  const float* W     = (const float*)d_in[2];
  const float* bias  = (const float*)d_in[3];

  float* out_embeds = (float*)d_out;                          // 65536*768 fp32
  float* fb_f32     = (float*)d_out + (size_t)M_TOTAL * HID;  // 65536*220 fp32

  bf16_t* Wb = (bf16_t*)d_ws;  // 768*224 bf16 = 344 KB

  convert_w_kernel<<<(HID * G8) / 256, 256, 0, stream>>>(W, Wb);

  fused_gather_gemm_kernel<<<M_TOTAL / 128, 256, 0, stream>>>(
      ids, table, Wb, bias, out_embeds, fb_f32);
}